// Round 22
// baseline (40.471 us; speedup 1.0000x reference)
//
#include <hip/hip_runtime.h>
#include <hip/hip_bf16.h>

namespace {
constexpr int kB = 2, kW = 5, kS = 5, kQ = 75, kC = 64, kHW = 441;
constexpr int kNP = 448;   // support positions padded (14 * 32)
constexpr int kMP = 448;   // query positions padded
constexpr int kCHUNK = 112;
constexpr int kLDT = 65;
constexpr int kTiles = kB * kQ * kW;              // 750
constexpr int kThreads = 448;                     // 7 waves: 2 col-tiles each
constexpr int kWaves = 7;
constexpr int kPrepGrid = 8 * 81;

typedef short bf16x8 __attribute__((ext_vector_type(8)));
typedef float f32x16 __attribute__((ext_vector_type(16)));
typedef __attribute__((address_space(3))) unsigned int lds_u32;
typedef const __attribute__((address_space(1))) unsigned int gbl_u32;
}

// ---- prep (R15-validated, plain stores): XCD-co-located shot-mean + L2-norm + transpose ----
__global__ __launch_bounds__(256) void prep_k(const float* __restrict__ sup,
                                              const float* __restrict__ qry,
                                              unsigned short* __restrict__ snT,
                                              unsigned short* __restrict__ qnT) {
  __shared__ float img_t[kCHUNK * kLDT];
  __shared__ float inv[kCHUNK];
  const int tid = threadIdx.x;
  const int x = blockIdx.x & 7;
  const int j = blockIdx.x >> 3;

  const int start0 = (x < 6) ? 94 * x : 564 + 93 * (x - 6);
  const int start1 = (x + 1 < 6) ? 94 * (x + 1) : 564 + 93 * (x + 1 - 6);
  const int lo = (start0 + 4) / 5, hi = (start1 + 4) / 5;
  const int nq = 4 * (hi - lo);

  bool is_sup;
  int bw = 0, bq = 0, chunk;
  if (j < nq) {
    is_sup = false;
    bq = lo + (j >> 2);
    chunk = j & 3;
  } else {
    int js = j - nq;
    if (js >= 5) return;
    is_sup = true;
    int u = x + 8 * js;
    bw = u >> 2;
    chunk = u & 3;
  }

  const int m0 = chunk * kCHUNK;
  const int mcnt = min(kCHUNK, kHW - m0);
  unsigned short* dst;

  if (is_sup) {
    const float* base = sup + (size_t)bw * kS * kC * kHW;
    for (int i = tid; i < kC * kCHUNK; i += 256) {
      int c = i / kCHUNK, mm = i % kCHUNK;
      float v = 0.f;
      if (mm < mcnt) {
        const float* p = base + (size_t)c * kHW + m0 + mm;
        float s = 0.f;
#pragma unroll
        for (int k = 0; k < kS; ++k) s += p[(size_t)k * kC * kHW];
        v = s * (1.f / kS);
      }
      img_t[mm * kLDT + c] = v;
    }
    dst = snT + (size_t)bw * kNP * kC;
  } else {
    const float* base = qry + (size_t)bq * kC * kHW;
    for (int i = tid; i < kC * kCHUNK; i += 256) {
      int c = i / kCHUNK, mm = i % kCHUNK;
      img_t[mm * kLDT + c] = (mm < mcnt) ? base[(size_t)c * kHW + m0 + mm] : 0.f;
    }
    dst = qnT + (size_t)bq * kMP * kC;
  }
  __syncthreads();

  if (tid < kCHUNK) {
    float ss = 0.f;
#pragma unroll
    for (int c = 0; c < kC; ++c) { float v = img_t[tid * kLDT + c]; ss += v * v; }
    inv[tid] = 1.f / fmaxf(sqrtf(ss), 1e-12f);
  }
  __syncthreads();

  for (int i8 = tid; i8 < kCHUNK * 8; i8 += 256) {
    int m = i8 >> 3, c8 = (i8 & 7) * 8;
    float sc = inv[m];
    union { unsigned short u[8]; uint4 v; } pk;
#pragma unroll
    for (int jj = 0; jj < 8; ++jj) {
      __hip_bfloat16 o = __float2bfloat16(img_t[m * kLDT + c8 + jj] * sc);
      pk.u[jj] = *reinterpret_cast<unsigned short*>(&o);
    }
    *reinterpret_cast<uint4*>(dst + ((size_t)(m0 + m) * kC + c8)) = pk.v;
  }
}

// ---- masked tail max (validated; no inline asm on MFMA outputs — R12 lesson) ----
__device__ __forceinline__ float max12_v(const f32x16& a) {
  float m0 = fmaxf(fmaxf(a[0], a[1]), a[2]);
  float m1 = fmaxf(fmaxf(a[3], a[4]), a[5]);
  float m2 = fmaxf(fmaxf(a[6], a[7]), a[8]);
  float m3 = fmaxf(fmaxf(a[9], a[10]), a[11]);
  return fmaxf(fmaxf(m0, m1), fmaxf(m2, m3));
}

// ---- main (R15 base): full staging, counted-vmcnt split; R22 changes:
//      (1) vm4 elementwise running max — 16->4 partial tree (depth 2) + 4
//      independent loop-carried chains, replacing the depth-5 serial tree +
//      scalar rm chain; (2) T5 setprio(1) around each MFMA cluster (waves
//      drift freely in the barrier-less tile loop -> phase-diverse regime). ----
__global__ __launch_bounds__(kThreads) void dn4_main_k(const unsigned short* __restrict__ qnT,
                                                       const unsigned short* __restrict__ snT,
                                                       float* __restrict__ out) {
  __shared__ __align__(16) unsigned short As[kNP * kC];  // 57344 B (2 blocks/CU)
  __shared__ float part[kWaves];
  const int tid = threadIdx.x;

  // bijective XCD-chunked mapping (750 = 6*94 + 2*93)
  const int xcd = blockIdx.x & 7, jj = blockIdx.x >> 3;
  const int idx = (xcd < 6) ? xcd * 94 + jj : 564 + (xcd - 6) * 93 + jj;

  const int w = idx % kW;
  const int bq = idx / kW;
  const int b = bq / kQ;

  const int lane = tid & 63;
  const int lh = lane >> 5;
  const int lm = lane & 31;
  const int wid = tid >> 6;          // 0..6
  const int ct0 = wid * 2;           // 2 col-tiles per wave, 14 total

  const unsigned short* sb = snT + (size_t)(b * kW + w) * kNP * kC;
  const unsigned short* qb = qnT + (size_t)bq * kMP * kC;
  const char* sbase = (const char*)sb;

  // query fragments issued first
  bf16x8 bf[2][4];
#pragma unroll
  for (int ct = 0; ct < 2; ++ct) {
    int m = (ct0 + ct) * 32 + lm;
#pragma unroll
    for (int kk = 0; kk < 4; ++kk)
      bf[ct][kk] = *reinterpret_cast<const bf16x8*>(qb + (size_t)m * kC + kk * 16 + lh * 8);
  }

  // stage all 448 rows: 3584 chunks = 8 rounds x 448. LDS linear dest,
  // pre-swizzled source (involution, validated R5..R21).
#pragma unroll
  for (int it = 0; it < 8; ++it) {
    int L = it * kThreads + tid;
    int srcj = (L & ~7) | ((L & 7) ^ ((L >> 3) & 7));
    __builtin_amdgcn_global_load_lds((gbl_u32*)(sbase + ((size_t)srcj << 4)),
                                     (lds_u32*)((char*)As + ((size_t)L << 4)), 16, 0, 0);
  }

  // vm4: 4-wide elementwise running max per col-tile (4 independent chains)
  float vm[2][4];
#pragma unroll
  for (int ct = 0; ct < 2; ++ct)
#pragma unroll
    for (int r = 0; r < 4; ++r) vm[ct][r] = -INFINITY;
  float tmax[2] = {-INFINITY, -INFINITY};

  asm volatile("s_waitcnt vmcnt(4)" ::: "memory");   // bf + rounds 0..3 landed
  __builtin_amdgcn_sched_barrier(0);
  __builtin_amdgcn_s_barrier();

  // tiles 0..6 from LDS rows 0..223 (runtime loop: full unroll spills — R6)
#pragma unroll 1
  for (int nt = 0; nt < 7; ++nt) {
    bf16x8 af[4];
    int n = nt * 32 + lm;
#pragma unroll
    for (int kk = 0; kk < 4; ++kk) {
      int k16 = kk * 2 + lh;
      af[kk] = *reinterpret_cast<const bf16x8*>(As + ((size_t)(n * 8 + (k16 ^ (n & 7))) << 3));
    }
#pragma unroll
    for (int ct = 0; ct < 2; ++ct) {
      f32x16 acc;
#pragma unroll
      for (int r = 0; r < 16; ++r) acc[r] = 0.f;
      __builtin_amdgcn_s_setprio(1);
#pragma unroll
      for (int kk = 0; kk < 4; ++kk)
        acc = __builtin_amdgcn_mfma_f32_32x32x16_bf16(af[kk], bf[ct][kk], acc, 0, 0, 0);
      __builtin_amdgcn_s_setprio(0);
      float p0 = fmaxf(fmaxf(acc[0], acc[1]), fmaxf(acc[2], acc[3]));
      float p1 = fmaxf(fmaxf(acc[4], acc[5]), fmaxf(acc[6], acc[7]));
      float p2 = fmaxf(fmaxf(acc[8], acc[9]), fmaxf(acc[10], acc[11]));
      float p3 = fmaxf(fmaxf(acc[12], acc[13]), fmaxf(acc[14], acc[15]));
      vm[ct][0] = fmaxf(vm[ct][0], p0);
      vm[ct][1] = fmaxf(vm[ct][1], p1);
      vm[ct][2] = fmaxf(vm[ct][2], p2);
      vm[ct][3] = fmaxf(vm[ct][3], p3);
    }
  }

  asm volatile("s_waitcnt vmcnt(0)" ::: "memory");   // all staging complete
  __builtin_amdgcn_sched_barrier(0);
  __builtin_amdgcn_s_barrier();

  // tiles 7..12
#pragma unroll 1
  for (int nt = 7; nt < 13; ++nt) {
    bf16x8 af[4];
    int n = nt * 32 + lm;
#pragma unroll
    for (int kk = 0; kk < 4; ++kk) {
      int k16 = kk * 2 + lh;
      af[kk] = *reinterpret_cast<const bf16x8*>(As + ((size_t)(n * 8 + (k16 ^ (n & 7))) << 3));
    }
#pragma unroll
    for (int ct = 0; ct < 2; ++ct) {
      f32x16 acc;
#pragma unroll
      for (int r = 0; r < 16; ++r) acc[r] = 0.f;
      __builtin_amdgcn_s_setprio(1);
#pragma unroll
      for (int kk = 0; kk < 4; ++kk)
        acc = __builtin_amdgcn_mfma_f32_32x32x16_bf16(af[kk], bf[ct][kk], acc, 0, 0, 0);
      __builtin_amdgcn_s_setprio(0);
      float p0 = fmaxf(fmaxf(acc[0], acc[1]), fmaxf(acc[2], acc[3]));
      float p1 = fmaxf(fmaxf(acc[4], acc[5]), fmaxf(acc[6], acc[7]));
      float p2 = fmaxf(fmaxf(acc[8], acc[9]), fmaxf(acc[10], acc[11]));
      float p3 = fmaxf(fmaxf(acc[12], acc[13]), fmaxf(acc[14], acc[15]));
      vm[ct][0] = fmaxf(vm[ct][0], p0);
      vm[ct][1] = fmaxf(vm[ct][1], p1);
      vm[ct][2] = fmaxf(vm[ct][2], p2);
      vm[ct][3] = fmaxf(vm[ct][3], p3);
    }
  }

  // tail tile nt=13 (rows 416..447; valid tile row <= 24; prep zero-pads but
  // mask anyway). row = (r&3)+8*(r>>2)+4*lh: lh0 invalid regs {13,14,15},
  // lh1 invalid {12..15} — masked scalar path (validated).
  {
    bf16x8 af[4];
    int n = 13 * 32 + lm;
#pragma unroll
    for (int kk = 0; kk < 4; ++kk) {
      int k16 = kk * 2 + lh;
      af[kk] = *reinterpret_cast<const bf16x8*>(As + ((size_t)(n * 8 + (k16 ^ (n & 7))) << 3));
    }
#pragma unroll
    for (int ct = 0; ct < 2; ++ct) {
      f32x16 acc;
#pragma unroll
      for (int r = 0; r < 16; ++r) acc[r] = 0.f;
      __builtin_amdgcn_s_setprio(1);
#pragma unroll
      for (int kk = 0; kk < 4; ++kk)
        acc = __builtin_amdgcn_mfma_f32_32x32x16_bf16(af[kk], bf[ct][kk], acc, 0, 0, 0);
      __builtin_amdgcn_s_setprio(0);
      float t = max12_v(acc);
      if (lh == 0) t = fmaxf(t, acc[12]);  // row 24 still valid
      tmax[ct] = fmaxf(tmax[ct], t);
    }
  }

  // final: tree-reduce vm4 + tail, combine complementary row-halves, sum cols
  float s = 0.f;
#pragma unroll
  for (int ct = 0; ct < 2; ++ct) {
    float c = fmaxf(fmaxf(fmaxf(vm[ct][0], vm[ct][1]), fmaxf(vm[ct][2], vm[ct][3])),
                    tmax[ct]);
    s += fmaxf(c, __shfl_xor(c, 32, 64));
  }
#pragma unroll
  for (int off = 1; off < 32; off <<= 1) s += __shfl_xor(s, off, 64);

  if (lane == 0) part[wid] = s;
  __syncthreads();
  if (tid == 0) {
    float t = 0.f;
#pragma unroll
    for (int v = 0; v < kWaves; ++v) t += part[v];
    out[idx] = t;
  }
}

extern "C" void kernel_launch(void* const* d_in, const int* in_sizes, int n_in,
                              void* d_out, int out_size, void* d_ws, size_t ws_size,
                              hipStream_t stream) {
  const float* sup = (const float*)d_in[0];
  const float* qry = (const float*)d_in[2];
  float* out = (float*)d_out;

  unsigned short* snT = (unsigned short*)d_ws;                 // 573,440 B
  unsigned short* qnT = snT + (size_t)kB * kW * kNP * kC;      // 8,601,600 B

  prep_k<<<kPrepGrid, 256, 0, stream>>>(sup, qry, snT, qnT);
  dn4_main_k<<<kTiles, kThreads, 0, stream>>>(qnT, snT, out);
}

// Round 23
// 38.793 us; speedup vs baseline: 1.0433x; 1.0433x over previous
//
#include <hip/hip_runtime.h>
#include <hip/hip_bf16.h>

namespace {
constexpr int kB = 2, kW = 5, kS = 5, kQ = 75, kC = 64, kHW = 441;
constexpr int kNP = 448;   // support positions padded (14 * 32)
constexpr int kMP = 448;   // query positions padded
constexpr int kCHUNK = 112;
constexpr int kLDT = 65;
constexpr int kTiles = kB * kQ * kW;              // 750
constexpr int kThreads = 448;                     // 7 waves: 2 col-tiles each
constexpr int kWaves = 7;
constexpr int kPrepGrid = 8 * 81;

typedef short bf16x8 __attribute__((ext_vector_type(8)));
typedef float f32x16 __attribute__((ext_vector_type(16)));
typedef __attribute__((address_space(3))) unsigned int lds_u32;
typedef const __attribute__((address_space(1))) unsigned int gbl_u32;
}

// ---- prep (R15-validated, unchanged): XCD-co-located shot-mean + L2-norm + transpose ----
__global__ __launch_bounds__(256) void prep_k(const float* __restrict__ sup,
                                              const float* __restrict__ qry,
                                              unsigned short* __restrict__ snT,
                                              unsigned short* __restrict__ qnT) {
  __shared__ float img_t[kCHUNK * kLDT];
  __shared__ float inv[kCHUNK];
  const int tid = threadIdx.x;
  const int x = blockIdx.x & 7;
  const int j = blockIdx.x >> 3;

  const int start0 = (x < 6) ? 94 * x : 564 + 93 * (x - 6);
  const int start1 = (x + 1 < 6) ? 94 * (x + 1) : 564 + 93 * (x + 1 - 6);
  const int lo = (start0 + 4) / 5, hi = (start1 + 4) / 5;
  const int nq = 4 * (hi - lo);

  bool is_sup;
  int bw = 0, bq = 0, chunk;
  if (j < nq) {
    is_sup = false;
    bq = lo + (j >> 2);
    chunk = j & 3;
  } else {
    int js = j - nq;
    if (js >= 5) return;
    is_sup = true;
    int u = x + 8 * js;
    bw = u >> 2;
    chunk = u & 3;
  }

  const int m0 = chunk * kCHUNK;
  const int mcnt = min(kCHUNK, kHW - m0);
  unsigned short* dst;

  if (is_sup) {
    const float* base = sup + (size_t)bw * kS * kC * kHW;
    for (int i = tid; i < kC * kCHUNK; i += 256) {
      int c = i / kCHUNK, mm = i % kCHUNK;
      float v = 0.f;
      if (mm < mcnt) {
        const float* p = base + (size_t)c * kHW + m0 + mm;
        float s = 0.f;
#pragma unroll
        for (int k = 0; k < kS; ++k) s += p[(size_t)k * kC * kHW];
        v = s * (1.f / kS);
      }
      img_t[mm * kLDT + c] = v;
    }
    dst = snT + (size_t)bw * kNP * kC;
  } else {
    const float* base = qry + (size_t)bq * kC * kHW;
    for (int i = tid; i < kC * kCHUNK; i += 256) {
      int c = i / kCHUNK, mm = i % kCHUNK;
      img_t[mm * kLDT + c] = (mm < mcnt) ? base[(size_t)c * kHW + m0 + mm] : 0.f;
    }
    dst = qnT + (size_t)bq * kMP * kC;
  }
  __syncthreads();

  if (tid < kCHUNK) {
    float ss = 0.f;
#pragma unroll
    for (int c = 0; c < kC; ++c) { float v = img_t[tid * kLDT + c]; ss += v * v; }
    inv[tid] = 1.f / fmaxf(sqrtf(ss), 1e-12f);
  }
  __syncthreads();

  for (int i8 = tid; i8 < kCHUNK * 8; i8 += 256) {
    int m = i8 >> 3, c8 = (i8 & 7) * 8;
    float sc = inv[m];
    union { unsigned short u[8]; uint4 v; } pk;
#pragma unroll
    for (int jj = 0; jj < 8; ++jj) {
      __hip_bfloat16 o = __float2bfloat16(img_t[m * kLDT + c8 + jj] * sc);
      pk.u[jj] = *reinterpret_cast<unsigned short*>(&o);
    }
    *reinterpret_cast<uint4*>(dst + ((size_t)(m0 + m) * kC + c8)) = pk.v;
  }
}

// ---- max helpers (validated; NO inline asm — R12 lesson) ----
__device__ __forceinline__ float max16_v(const f32x16& a) {
  float m0 = fmaxf(fmaxf(a[0], a[1]), a[2]);
  float m1 = fmaxf(fmaxf(a[3], a[4]), a[5]);
  float m2 = fmaxf(fmaxf(a[6], a[7]), a[8]);
  float m3 = fmaxf(fmaxf(a[9], a[10]), a[11]);
  float m4 = fmaxf(fmaxf(a[12], a[13]), a[14]);
  return fmaxf(fmaxf(fmaxf(m0, m1), m2), fmaxf(fmaxf(m3, m4), a[15]));
}
__device__ __forceinline__ float max12_v(const f32x16& a) {
  float m0 = fmaxf(fmaxf(a[0], a[1]), a[2]);
  float m1 = fmaxf(fmaxf(a[3], a[4]), a[5]);
  float m2 = fmaxf(fmaxf(a[6], a[7]), a[8]);
  float m3 = fmaxf(fmaxf(a[9], a[10]), a[11]);
  return fmaxf(fmaxf(m0, m1), fmaxf(m2, m3));
}

// ---- main (R15 base + R23: per-wave tile-order ROTATION to break the
//      post-barrier convoy — all waves ran the identical sequence in phase,
//      so MFMA/VALU/LDS demands peaked together (R8: MfmaUtil 35 + VALUBusy 34,
//      sequential). Rotation staggers each wave's position in the tile loop;
//      max-reduction is order-independent, so this is a free permutation. ----
__global__ __launch_bounds__(kThreads) void dn4_main_k(const unsigned short* __restrict__ qnT,
                                                       const unsigned short* __restrict__ snT,
                                                       float* __restrict__ out) {
  __shared__ __align__(16) unsigned short As[kNP * kC];  // 57344 B (2 blocks/CU)
  __shared__ float part[kWaves];
  const int tid = threadIdx.x;

  // bijective XCD-chunked mapping (750 = 6*94 + 2*93)
  const int xcd = blockIdx.x & 7, jj = blockIdx.x >> 3;
  const int idx = (xcd < 6) ? xcd * 94 + jj : 564 + (xcd - 6) * 93 + jj;

  const int w = idx % kW;
  const int bq = idx / kW;
  const int b = bq / kQ;

  const int lane = tid & 63;
  const int lh = lane >> 5;
  const int lm = lane & 31;
  const int wid = tid >> 6;          // 0..6
  const int ct0 = wid * 2;           // 2 col-tiles per wave, 14 total

  const unsigned short* sb = snT + (size_t)(b * kW + w) * kNP * kC;
  const unsigned short* qb = qnT + (size_t)bq * kMP * kC;
  const char* sbase = (const char*)sb;

  // query fragments issued first
  bf16x8 bf[2][4];
#pragma unroll
  for (int ct = 0; ct < 2; ++ct) {
    int m = (ct0 + ct) * 32 + lm;
#pragma unroll
    for (int kk = 0; kk < 4; ++kk)
      bf[ct][kk] = *reinterpret_cast<const bf16x8*>(qb + (size_t)m * kC + kk * 16 + lh * 8);
  }

  // stage all 448 rows: 3584 chunks = 8 rounds x 448. LDS linear dest,
  // pre-swizzled source (involution, validated R5..R22).
#pragma unroll
  for (int it = 0; it < 8; ++it) {
    int L = it * kThreads + tid;
    int srcj = (L & ~7) | ((L & 7) ^ ((L >> 3) & 7));
    __builtin_amdgcn_global_load_lds((gbl_u32*)(sbase + ((size_t)srcj << 4)),
                                     (lds_u32*)((char*)As + ((size_t)L << 4)), 16, 0, 0);
  }

  f32x16 z;
#pragma unroll
  for (int r = 0; r < 16; ++r) z[r] = 0.f;
  float rm[2] = {-INFINITY, -INFINITY};

  asm volatile("s_waitcnt vmcnt(4)" ::: "memory");   // bf + rounds 0..3 landed
  __builtin_amdgcn_sched_barrier(0);
  __builtin_amdgcn_s_barrier();

  // phase 1: tiles 0..6 (rows 0..223), ROTATED start: wave wid begins at tile
  // wid and wraps — 7 waves on 7 distinct tiles -> de-convoyed pipes.
#pragma unroll 1
  for (int i = 0; i < 7; ++i) {
    int nt = wid + i; if (nt >= 7) nt -= 7;
    bf16x8 af[4];
    int n = nt * 32 + lm;
#pragma unroll
    for (int kk = 0; kk < 4; ++kk) {
      int k16 = kk * 2 + lh;
      af[kk] = *reinterpret_cast<const bf16x8*>(As + ((size_t)(n * 8 + (k16 ^ (n & 7))) << 3));
    }
#pragma unroll
    for (int ct = 0; ct < 2; ++ct) {
      f32x16 acc = z;
#pragma unroll
      for (int kk = 0; kk < 4; ++kk)
        acc = __builtin_amdgcn_mfma_f32_32x32x16_bf16(af[kk], bf[ct][kk], acc, 0, 0, 0);
      rm[ct] = fmaxf(rm[ct], max16_v(acc));
    }
  }

  asm volatile("s_waitcnt vmcnt(0)" ::: "memory");   // all staging complete
  __builtin_amdgcn_sched_barrier(0);
  __builtin_amdgcn_s_barrier();

  // phase 2: tiles 7..12, rotated start at wid mod 6
  const int r0 = (wid >= 6) ? 0 : wid;
#pragma unroll 1
  for (int i = 0; i < 6; ++i) {
    int nt = r0 + i; if (nt >= 6) nt -= 6;
    nt += 7;
    bf16x8 af[4];
    int n = nt * 32 + lm;
#pragma unroll
    for (int kk = 0; kk < 4; ++kk) {
      int k16 = kk * 2 + lh;
      af[kk] = *reinterpret_cast<const bf16x8*>(As + ((size_t)(n * 8 + (k16 ^ (n & 7))) << 3));
    }
#pragma unroll
    for (int ct = 0; ct < 2; ++ct) {
      f32x16 acc = z;
#pragma unroll
      for (int kk = 0; kk < 4; ++kk)
        acc = __builtin_amdgcn_mfma_f32_32x32x16_bf16(af[kk], bf[ct][kk], acc, 0, 0, 0);
      rm[ct] = fmaxf(rm[ct], max16_v(acc));
    }
  }

  // tail tile nt=13 (rows 416..447; valid tile row <= 24; prep zero-pads but
  // mask anyway — zeros could beat all-negative sims).
  // row = (r&3)+8*(r>>2)+4*lh: lh0 invalid regs {13,14,15}, lh1 invalid {12..15}
  {
    bf16x8 af[4];
    int n = 13 * 32 + lm;
#pragma unroll
    for (int kk = 0; kk < 4; ++kk) {
      int k16 = kk * 2 + lh;
      af[kk] = *reinterpret_cast<const bf16x8*>(As + ((size_t)(n * 8 + (k16 ^ (n & 7))) << 3));
    }
#pragma unroll
    for (int ct = 0; ct < 2; ++ct) {
      f32x16 acc = z;
#pragma unroll
      for (int kk = 0; kk < 4; ++kk)
        acc = __builtin_amdgcn_mfma_f32_32x32x16_bf16(af[kk], bf[ct][kk], acc, 0, 0, 0);
      float t = max12_v(acc);
      if (lh == 0) t = fmaxf(t, acc[12]);  // row 24 still valid
      rm[ct] = fmaxf(rm[ct], t);
    }
  }

  // combine complementary row-halves, then sum this wave's 64 columns
  float s = fmaxf(rm[0], __shfl_xor(rm[0], 32, 64)) +
            fmaxf(rm[1], __shfl_xor(rm[1], 32, 64));
#pragma unroll
  for (int off = 1; off < 32; off <<= 1) s += __shfl_xor(s, off, 64);

  if (lane == 0) part[wid] = s;
  __syncthreads();
  if (tid == 0) {
    float t = 0.f;
#pragma unroll
    for (int v = 0; v < kWaves; ++v) t += part[v];
    out[idx] = t;
  }
}

extern "C" void kernel_launch(void* const* d_in, const int* in_sizes, int n_in,
                              void* d_out, int out_size, void* d_ws, size_t ws_size,
                              hipStream_t stream) {
  const float* sup = (const float*)d_in[0];
  const float* qry = (const float*)d_in[2];
  float* out = (float*)d_out;

  unsigned short* snT = (unsigned short*)d_ws;                 // 573,440 B
  unsigned short* qnT = snT + (size_t)kB * kW * kNP * kC;      // 8,601,600 B

  prep_k<<<kPrepGrid, 256, 0, stream>>>(sup, qry, snT, qnT);
  dn4_main_k<<<kTiles, kThreads, 0, stream>>>(qnT, snT, out);
}